// Round 4
// baseline (574.234 us; speedup 1.0000x reference)
//
#include <hip/hip_runtime.h>
#include <cmath>

namespace {

constexpr int CH    = 512;
constexpr int NPIX  = 4096;   // 64*64

typedef _Float16 half8 __attribute__((ext_vector_type(8)));
typedef _Float16 half4 __attribute__((ext_vector_type(4)));
typedef float    f32x4 __attribute__((ext_vector_type(4)));

__device__ __forceinline__ float sigmoidf_(float v) { return 1.0f / (1.0f + expf(-v)); }
__device__ __forceinline__ float elu1_(float v)     { return v > 0.0f ? v + 1.0f : expf(v); }

// ======================= K0: fp32 -> (hi, lo*1024) f16 split ==============
__global__ __launch_bounds__(256) void k_split(
    const float4* __restrict__ in, half4* __restrict__ hi,
    half4* __restrict__ lo, int n4)
{
    int i = blockIdx.x * 256 + threadIdx.x;
    if (i >= n4) return;
    float4 v = in[i];
    half4 h, l;
    h[0] = (_Float16)v.x; l[0] = (_Float16)((v.x - (float)h[0]) * 1024.0f);
    h[1] = (_Float16)v.y; l[1] = (_Float16)((v.y - (float)h[1]) * 1024.0f);
    h[2] = (_Float16)v.z; l[2] = (_Float16)((v.z - (float)h[2]) * 1024.0f);
    h[3] = (_Float16)v.w; l[3] = (_Float16)((v.w - (float)h[3]) * 1024.0f);
    hi[i] = h; lo[i] = l;
}

// ======================= K1: qk = x @ qk_w^T + qk_b (split-f16 MFMA) ======
__global__ __launch_bounds__(256, 2) void k_gemm_mfma(
    const _Float16* __restrict__ Ahi, const _Float16* __restrict__ Alo,
    const _Float16* __restrict__ Bhi, const _Float16* __restrict__ Blo,
    const float* __restrict__ bias, float* __restrict__ out)
{
    __shared__ _Float16 lds[4 * 128 * 32];   // Ahi | Alo | Bhi | Blo tiles
    const int t    = threadIdx.x;
    const int wave = t >> 6;
    const int lane = t & 63;
    const int bm   = blockIdx.x;             // 0..255
    const int bn   = blockIdx.y;             // 0..7

    const _Float16* src;
    switch (wave) {
        case 0: src = Ahi + (size_t)bm * 128 * 512; break;
        case 1: src = Alo + (size_t)bm * 128 * 512; break;
        case 2: src = Bhi + (size_t)bn * 128 * 512; break;
        default: src = Blo + (size_t)bn * 128 * 512; break;
    }
    const _Float16* srcLane = src + (size_t)(lane >> 2) * 512 + (lane & 3) * 8;
    _Float16* ldsW = lds + wave * 4096;

    const int wm = wave >> 1, wn = wave & 1;
    const int mrow = lane & 15;
    const int kq   = (lane >> 4) * 8;
    const _Float16* aH = lds         + (wm * 64 + mrow) * 32 + kq;
    const _Float16* aL = lds + 4096  + (wm * 64 + mrow) * 32 + kq;
    const _Float16* bH = lds + 8192  + (wn * 64 + mrow) * 32 + kq;
    const _Float16* bL = lds + 12288 + (wn * 64 + mrow) * 32 + kq;

    f32x4 acc0[4][4], acc1[4][4];
    #pragma unroll
    for (int i = 0; i < 4; i++)
        #pragma unroll
        for (int j = 0; j < 4; j++) { acc0[i][j] = (f32x4)0.0f; acc1[i][j] = (f32x4)0.0f; }

    for (int k0 = 0; k0 < 16; k0++) {
        const _Float16* g = srcLane + k0 * 32;
        #pragma unroll
        for (int r = 0; r < 8; r++) {
            __builtin_amdgcn_global_load_lds(
                (const __attribute__((address_space(1))) void*)(g + (size_t)r * 16 * 512),
                (__attribute__((address_space(3))) void*)(ldsW + r * 512),
                16, 0, 0);
        }
        __syncthreads();

        half8 ah[4], al[4], bh[4], bl[4];
        #pragma unroll
        for (int i = 0; i < 4; i++) {
            ah[i] = *(const half8*)(aH + i * 16 * 32);
            al[i] = *(const half8*)(aL + i * 16 * 32);
            bh[i] = *(const half8*)(bH + i * 16 * 32);
            bl[i] = *(const half8*)(bL + i * 16 * 32);
        }
        #pragma unroll
        for (int i = 0; i < 4; i++)
            #pragma unroll
            for (int j = 0; j < 4; j++) {
                acc0[i][j] = __builtin_amdgcn_mfma_f32_16x16x32_f16(ah[i], bh[j], acc0[i][j], 0, 0, 0);
                acc1[i][j] = __builtin_amdgcn_mfma_f32_16x16x32_f16(ah[i], bl[j], acc1[i][j], 0, 0, 0);
                acc1[i][j] = __builtin_amdgcn_mfma_f32_16x16x32_f16(al[i], bh[j], acc1[i][j], 0, 0, 0);
            }
        __syncthreads();
    }

    const int ccol = lane & 15;
    const int crow = (lane >> 4) * 4;
    #pragma unroll
    for (int j = 0; j < 4; j++) {
        int col = bn * 128 + wn * 64 + j * 16 + ccol;
        float bv = bias[col];
        #pragma unroll
        for (int i = 0; i < 4; i++) {
            size_t row0 = (size_t)bm * 128 + wm * 64 + i * 16 + crow;
            #pragma unroll
            for (int r = 0; r < 4; r++) {
                float v = acc0[i][j][r] + acc1[i][j][r] * (1.0f / 1024.0f) + bv;
                out[(row0 + r) * 1024 + col] = v;
            }
        }
    }
}

// ======================= K2: spatial gate + (which==0) lepe conv ===========
// Block = (b, h, w-quarter, which); 512 threads = channels. Sliding 3x3
// window on qk-half; which==0 blocks also compute the lepe dwconv on x and
// write out = lepe (k_attn RMW-adds attention afterwards).
__global__ __launch_bounds__(512) void k_spatial(
    const float* __restrict__ qk, const float* __restrict__ x,
    const float* __restrict__ dw_w_q, const float* __restrict__ dw_b_q,
    const float* __restrict__ bn_g_q, const float* __restrict__ bn_b_q,
    const float* __restrict__ pw_q,
    const float* __restrict__ dw_w_k, const float* __restrict__ dw_b_k,
    const float* __restrict__ bn_g_k, const float* __restrict__ bn_b_k,
    const float* __restrict__ pw_k,
    const float* __restrict__ lepe_w, const float* __restrict__ lepe_b,
    float* __restrict__ s_sp_q, float* __restrict__ s_sp_k,
    float* __restrict__ pool_q, float* __restrict__ pool_k,
    float* __restrict__ out)
{
    const int which = blockIdx.y;
    const int bx = blockIdx.x;            // 0..2047
    const int b  = bx >> 8;
    const int h  = (bx >> 2) & 63;
    const int w0 = (bx & 3) * 16;
    const int c  = threadIdx.x;
    const float* dw_w = which ? dw_w_k : dw_w_q;
    const float* dw_b = which ? dw_b_k : dw_b_q;
    const float* bn_g = which ? bn_g_k : bn_g_q;
    const float* bn_b = which ? bn_b_k : bn_b_q;
    const float* pw   = which ? pw_k   : pw_q;
    float*       s_sp = which ? s_sp_k : s_sp_q;
    float*       pool = which ? pool_k : pool_q;

    float w9[9];
    #pragma unroll
    for (int j = 0; j < 9; j++) w9[j] = dw_w[c * 9 + j];
    const float bconv = dw_b[c];
    const float bns   = bn_g[c] * (1.0f / sqrtf(1.00001f));
    const float bnb   = bn_b[c];
    const float pwc   = pw[c];

    // lepe weights (only used by which==0)
    float l9[9]; float lbias = 0.0f;
    if (!which) {
        #pragma unroll
        for (int j = 0; j < 9; j++) l9[j] = lepe_w[c * 9 + j];
        lbias = lepe_b[c];
    }

    __shared__ float wavepart[16][8];
    __shared__ float s_row[16];
    const int lane = c & 63, wid = c >> 6;
    const float* inb  = qk + (size_t)b * NPIX * 1024 + (which ? 512 : 0);
    const float* row0 = inb + (size_t)(h * 64) * 1024 + c;
    const float* rowm = row0 - (ptrdiff_t)64 * 1024;
    const float* rowp = row0 + (ptrdiff_t)64 * 1024;
    const float* xr0  = x + ((size_t)b * NPIX + h * 64) * 512 + c;
    const float* xrm  = xr0 - (ptrdiff_t)64 * 512;
    const float* xrp  = xr0 + (ptrdiff_t)64 * 512;
    float* outb = out + ((size_t)b * NPIX + h * 64) * 512 + c;
    const bool hm_ok = (h > 0), hp_ok = (h < 63);

    float a0m, a00, a0p, a1m, a10, a1p, a2m, a20, a2p;   // qk window
    float y0m, y00, y0p, y1m, y10, y1p, y2m, y20, y2p;   // x window (lepe)
    float cent[16];

    auto LD3Q = [&](int wg, float& vm, float& v0, float& vp) {
        bool wok = (wg >= 0) && (wg < 64);
        ptrdiff_t o = (ptrdiff_t)wg * 1024;
        vm = (wok && hm_ok) ? rowm[o] : 0.0f;
        v0 =  wok           ? row0[o] : 0.0f;
        vp = (wok && hp_ok) ? rowp[o] : 0.0f;
    };
    auto LD3X = [&](int wg, float& vm, float& v0, float& vp) {
        bool wok = (wg >= 0) && (wg < 64);
        ptrdiff_t o = (ptrdiff_t)wg * 512;
        vm = (wok && hm_ok) ? xrm[o] : 0.0f;
        v0 =  wok           ? xr0[o] : 0.0f;
        vp = (wok && hp_ok) ? xrp[o] : 0.0f;
    };

    LD3Q(w0 - 1, a0m, a1m, a2m);
    LD3Q(w0,     a00, a10, a20);
    if (!which) {
        LD3X(w0 - 1, y0m, y1m, y2m);
        LD3X(w0,     y00, y10, y20);
    }

    #pragma unroll
    for (int i = 0; i < 16; i++) {
        LD3Q(w0 + i + 1, a0p, a1p, a2p);
        float y = bconv;
        y = fmaf(a0m, w9[0], y); y = fmaf(a00, w9[1], y); y = fmaf(a0p, w9[2], y);
        y = fmaf(a1m, w9[3], y); y = fmaf(a10, w9[4], y); y = fmaf(a1p, w9[5], y);
        y = fmaf(a2m, w9[6], y); y = fmaf(a20, w9[7], y); y = fmaf(a2p, w9[8], y);
        y = fmaxf(fmaf(y, bns, bnb), 0.0f);
        cent[i] = a10;
        float contrib = y * pwc;
        #pragma unroll
        for (int o = 32; o > 0; o >>= 1) contrib += __shfl_down(contrib, o, 64);
        if (lane == 0) wavepart[i][wid] = contrib;
        a0m = a00; a00 = a0p;
        a1m = a10; a10 = a1p;
        a2m = a20; a20 = a2p;

        if (!which) {
            float y0p_, y1p_, y2p_;
            LD3X(w0 + i + 1, y0p_, y1p_, y2p_);
            y0p = y0p_; y1p = y1p_; y2p = y2p_;
            float lp = lbias;
            lp = fmaf(y0m, l9[0], lp); lp = fmaf(y00, l9[1], lp); lp = fmaf(y0p, l9[2], lp);
            lp = fmaf(y1m, l9[3], lp); lp = fmaf(y10, l9[4], lp); lp = fmaf(y1p, l9[5], lp);
            lp = fmaf(y2m, l9[6], lp); lp = fmaf(y20, l9[7], lp); lp = fmaf(y2p, l9[8], lp);
            outb[(size_t)(w0 + i) * 512] = lp;
            y0m = y00; y00 = y0p;
            y1m = y10; y10 = y1p;
            y2m = y20; y20 = y2p;
        }
    }
    __syncthreads();
    if (c < 16) {
        float s = 0.0f;
        #pragma unroll
        for (int j = 0; j < 8; j++) s += wavepart[c][j];
        s = sigmoidf_(s);
        s_row[c] = s;
        s_sp[(size_t)b * NPIX + h * 64 + w0 + c] = s;
    }
    __syncthreads();
    float pacc = 0.0f;
    #pragma unroll
    for (int i = 0; i < 16; i++) pacc = fmaf(cent[i], s_row[i], pacc);
    atomicAdd(&pool[(size_t)b * CH + c], pacc);
}

// ======================= K3: channel sigmoid ===============================
__global__ __launch_bounds__(256) void k_chsig(
    const float* __restrict__ pool_q, const float* __restrict__ pool_k,
    const float* __restrict__ qch_w,  const float* __restrict__ kch_w,
    float* __restrict__ sch_q, float* __restrict__ sch_k)
{
    int id    = blockIdx.x;           // 0..2047
    int which = id >> 10;
    int rem   = id & 1023;
    int b     = rem >> 7;             // 0..7
    int og    = rem & 127;            // 0..127
    int wid   = threadIdx.x >> 6, lane = threadIdx.x & 63;
    int o     = og * 4 + wid;
    const float* pool = which ? pool_k : pool_q;
    const float* Wt   = which ? kch_w  : qch_w;
    float s = 0.0f;
    for (int cc = lane; cc < CH; cc += 64) s = fmaf(pool[b * CH + cc], Wt[o * CH + cc], s);
    #pragma unroll
    for (int off = 32; off > 0; off >>= 1) s += __shfl_down(s, off, 64);
    if (lane == 0)
        (which ? sch_k : sch_q)[b * CH + o] = sigmoidf_(s * (1.0f / 4096.0f));
}

// ======================= K5: kvT[b,h,e,d] = sum_n k_r[n,d]*x[n,e] ==========
// Gate+elu+RoPE applied on-the-fly during staging (rope pairs are adjacent
// within the float4 - no shfl). Also accumulates kmean (raw sum over n).
__global__ __launch_bounds__(256) void k_kv(
    const float* __restrict__ qk, const float* __restrict__ x,
    const float* __restrict__ s_sp_k, const float* __restrict__ sch_k,
    const float* __restrict__ cosT, const float* __restrict__ sinT,
    float* __restrict__ kvT, float* __restrict__ kmean)
{
    const int bh = blockIdx.x;      // 0..127
    const int b  = bh >> 4, hh = bh & 15;
    const int n0 = blockIdx.y * 512;
    __shared__ float kt[32][33];
    __shared__ float vt[32][33];
    const int t  = threadIdx.x;
    const int e  = t & 31, d0 = (t >> 5) * 4;
    const int nn  = t >> 3;
    const int cc4 = (t & 7) * 4;
    const int ck  = hh * 32 + cc4;                 // channel within k-tensor
    const float4 sch4 = *(const float4*)(sch_k + b * CH + ck);
    const int kidx0 = ck >> 1;
    float acc[4] = {0.f, 0.f, 0.f, 0.f};
    float kmp[4] = {0.f, 0.f, 0.f, 0.f};
    for (int s = 0; s < 512; s += 32) {
        const int npix = n0 + s + nn;
        const size_t rowbase = (size_t)b * NPIX + npix;
        float4 kr = *(const float4*)(qk + rowbase * 1024 + 512 + ck);
        float ssp = s_sp_k[rowbase];
        float2 c2 = *(const float2*)(cosT + (size_t)npix * 256 + kidx0);
        float2 s2 = *(const float2*)(sinT + (size_t)npix * 256 + kidx0);
        float e0 = elu1_(kr.x * ssp * sch4.x);
        float e1 = elu1_(kr.y * ssp * sch4.y);
        float e2 = elu1_(kr.z * ssp * sch4.z);
        float e3 = elu1_(kr.w * ssp * sch4.w);
        float r0 = c2.x * e0 - s2.x * e1;
        float r1 = s2.x * e0 + c2.x * e1;
        float r2 = c2.y * e2 - s2.y * e3;
        float r3 = s2.y * e2 + c2.y * e3;
        kmp[0] += r0; kmp[1] += r1; kmp[2] += r2; kmp[3] += r3;
        kt[nn][cc4] = r0; kt[nn][cc4+1] = r1; kt[nn][cc4+2] = r2; kt[nn][cc4+3] = r3;
        float4 vv = *(const float4*)(x + rowbase * 512 + hh * 32 + cc4);
        vt[nn][cc4] = vv.x; vt[nn][cc4+1] = vv.y; vt[nn][cc4+2] = vv.z; vt[nn][cc4+3] = vv.w;
        __syncthreads();
        #pragma unroll
        for (int q = 0; q < 32; q++) {
            float vq = vt[q][e];
            acc[0] = fmaf(kt[q][d0    ], vq, acc[0]);
            acc[1] = fmaf(kt[q][d0 + 1], vq, acc[1]);
            acc[2] = fmaf(kt[q][d0 + 2], vq, acc[2]);
            acc[3] = fmaf(kt[q][d0 + 3], vq, acc[3]);
        }
        __syncthreads();
    }
    #pragma unroll
    for (int i = 0; i < 4; i++)
        atomicAdd(&kvT[((size_t)bh * 32 + e) * 32 + d0 + i], acc[i]);   // [e][d]
    #pragma unroll
    for (int i = 0; i < 4; i++)
        atomicAdd(&kmean[(size_t)b * CH + ck + i], kmp[i]);
}

// ======================= K6: out += (q_rope @ kv) * z  (split-f16 MFMA) ====
// Block = (b, h-row, half); 4 waves: 2 m-tiles x 2 head-groups. Gate+elu+
// RoPE on q computed in-register while building A fragments. den in exact
// fp32 (per-lane dot + 2 shfl_xor). RMW-adds onto out (lepe already there).
__global__ __launch_bounds__(256) void k_attn(
    const float* __restrict__ qk, const float* __restrict__ kvT,
    const float* __restrict__ kmean, const float* __restrict__ s_sp_q,
    const float* __restrict__ sch_q, const float* __restrict__ cosT,
    const float* __restrict__ sinT, float* __restrict__ out)
{
    const int bx   = blockIdx.x;          // 0..1023
    const int b    = bx >> 7;
    const int h    = (bx >> 1) & 63;
    const int half = bx & 1;
    const int t    = threadIdx.x;
    const int wave = t >> 6, lane = t & 63;
    const int mt   = wave >> 1;           // m-tile within half-row
    const int hg   = wave & 1;            // head group (8 heads each)
    const int m    = lane & 15, quad = lane >> 4;
    const int nrow0 = h * 64 + half * 32 + mt * 16;
    const int n     = nrow0 + m;
    const size_t nb = (size_t)b * NPIX + n;
    const float ssp = s_sp_q[nb];
    const float* qrow = qk + nb * 1024;
    const float* cosn = cosT + (size_t)n * 256;
    const float* sinn = sinT + (size_t)n * 256;

    for (int hi = 0; hi < 8; hi++) {
        const int head = hg * 8 + hi;
        const int c0   = head * 32 + quad * 8;
        float4 qa = *(const float4*)(qrow + c0);
        float4 qb = *(const float4*)(qrow + c0 + 4);
        float4 sa = *(const float4*)(sch_q + b * CH + c0);
        float4 sb = *(const float4*)(sch_q + b * CH + c0 + 4);
        const int kidx0 = head * 16 + quad * 4;
        float4 cs = *(const float4*)(cosn + kidx0);
        float4 sn = *(const float4*)(sinn + kidx0);
        float e0 = elu1_(qa.x * ssp * sa.x), e1 = elu1_(qa.y * ssp * sa.y);
        float e2 = elu1_(qa.z * ssp * sa.z), e3 = elu1_(qa.w * ssp * sa.w);
        float e4 = elu1_(qb.x * ssp * sb.x), e5 = elu1_(qb.y * ssp * sb.y);
        float e6 = elu1_(qb.z * ssp * sb.z), e7 = elu1_(qb.w * ssp * sb.w);
        float r0 = cs.x * e0 - sn.x * e1, r1 = sn.x * e0 + cs.x * e1;
        float r2 = cs.y * e2 - sn.y * e3, r3 = sn.y * e2 + cs.y * e3;
        float r4 = cs.z * e4 - sn.z * e5, r5 = sn.z * e4 + cs.z * e5;
        float r6 = cs.w * e6 - sn.w * e7, r7 = sn.w * e6 + cs.w * e7;

        // den: exact fp32 per-lane partial dot, reduce across the 4 quads
        float4 ka = *(const float4*)(kmean + b * CH + c0);
        float4 kb = *(const float4*)(kmean + b * CH + c0 + 4);
        float den = r0 * ka.x + r1 * ka.y + r2 * ka.z + r3 * ka.w
                  + r4 * kb.x + r5 * kb.y + r6 * kb.z + r7 * kb.w;
        den += __shfl_xor(den, 16, 64);
        den += __shfl_xor(den, 32, 64);
        const float z = 1.0f / (den * (1.0f / 4096.0f) + 1e-6f);

        // A fragment (hi/lo split)
        half8 ah, al;
        float rr[8] = {r0, r1, r2, r3, r4, r5, r6, r7};
        #pragma unroll
        for (int j = 0; j < 8; j++) {
            ah[j] = (_Float16)rr[j];
            al[j] = (_Float16)((rr[j] - (float)ah[j]) * 1024.0f);
        }
        // B fragments: kvT[e][d]/4096, n = lane&15 (+16 for ntile1), k = quad*8..+7
        const float* kvb = kvT + (((size_t)(b * 16 + head) * 32 + m) * 32) + quad * 8;
        float4 b0a = *(const float4*)(kvb);
        float4 b0b = *(const float4*)(kvb + 4);
        float4 b1a = *(const float4*)(kvb + 16 * 32);
        float4 b1b = *(const float4*)(kvb + 16 * 32 + 4);
        half8 bh0, bl0, bh1, bl1;
        float b0[8] = {b0a.x, b0a.y, b0a.z, b0a.w, b0b.x, b0b.y, b0b.z, b0b.w};
        float b1[8] = {b1a.x, b1a.y, b1a.z, b1a.w, b1b.x, b1b.y, b1b.z, b1b.w};
        #pragma unroll
        for (int j = 0; j < 8; j++) {
            float v0 = b0[j] * (1.0f / 4096.0f);
            float v1 = b1[j] * (1.0f / 4096.0f);
            bh0[j] = (_Float16)v0; bl0[j] = (_Float16)((v0 - (float)bh0[j]) * 1024.0f);
            bh1[j] = (_Float16)v1; bl1[j] = (_Float16)((v1 - (float)bh1[j]) * 1024.0f);
        }

        f32x4 a0h = (f32x4)0.0f, a0x = (f32x4)0.0f;
        f32x4 a1h = (f32x4)0.0f, a1x = (f32x4)0.0f;
        a0h = __builtin_amdgcn_mfma_f32_16x16x32_f16(ah, bh0, a0h, 0, 0, 0);
        a0x = __builtin_amdgcn_mfma_f32_16x16x32_f16(ah, bl0, a0x, 0, 0, 0);
        a0x = __builtin_amdgcn_mfma_f32_16x16x32_f16(al, bh0, a0x, 0, 0, 0);
        a1h = __builtin_amdgcn_mfma_f32_16x16x32_f16(ah, bh1, a1h, 0, 0, 0);
        a1x = __builtin_amdgcn_mfma_f32_16x16x32_f16(ah, bl1, a1x, 0, 0, 0);
        a1x = __builtin_amdgcn_mfma_f32_16x16x32_f16(al, bh1, a1x, 0, 0, 0);

        // epilogue: C row = quad*4+r (pixel), col = lane&15 (+16)
        float* op = out + ((size_t)b * NPIX + nrow0 + quad * 4) * 512 + head * 32 + m;
        #pragma unroll
        for (int r = 0; r < 4; r++) {
            float zr = __shfl(z, quad * 4 + r, 64);
            float v0 = (a0h[r] + a0x[r] * (1.0f / 1024.0f)) * zr;
            float v1 = (a1h[r] + a1x[r] * (1.0f / 1024.0f)) * zr;
            op[(size_t)r * 512]      += v0;
            op[(size_t)r * 512 + 16] += v1;
        }
    }
}

} // namespace

extern "C" void kernel_launch(void* const* d_in, const int* in_sizes, int n_in,
                              void* d_out, int out_size, void* d_ws, size_t ws_size,
                              hipStream_t stream)
{
    (void)in_sizes; (void)n_in; (void)out_size; (void)ws_size;
    const float* x        = (const float*)d_in[0];
    const float* qk_w     = (const float*)d_in[1];
    const float* qk_b     = (const float*)d_in[2];
    const float* qsp_dw_w = (const float*)d_in[3];
    const float* qsp_dw_b = (const float*)d_in[4];
    const float* qsp_bn_g = (const float*)d_in[5];
    const float* qsp_bn_b = (const float*)d_in[6];
    const float* qsp_pw_w = (const float*)d_in[7];
    const float* qch_w    = (const float*)d_in[8];
    const float* ksp_dw_w = (const float*)d_in[9];
    const float* ksp_dw_b = (const float*)d_in[10];
    const float* ksp_bn_g = (const float*)d_in[11];
    const float* ksp_bn_b = (const float*)d_in[12];
    const float* ksp_pw_w = (const float*)d_in[13];
    const float* kch_w    = (const float*)d_in[14];
    const float* lepe_w   = (const float*)d_in[15];
    const float* lepe_b   = (const float*)d_in[16];
    const float* rope_cos = (const float*)d_in[17];
    const float* rope_sin = (const float*)d_in[18];

    float* ws     = (float*)d_ws;
    float* qk     = ws;                       // 33554432 floats (128 MB), stays RAW
    float* s_sp_q = qk + 33554432;            // 32768
    float* s_sp_k = s_sp_q + 32768;           // 32768
    float* sch_q  = s_sp_k + 32768;           // 4096
    float* sch_k  = sch_q + 4096;             // 4096
    float* pool_q = sch_k + 4096;             // 4096  <- zeroed region starts here
    float* pool_k = pool_q + 4096;            // 4096
    float* kmean  = pool_k + 4096;            // 4096
    float* kvT    = kmean + 4096;             // 131072  [b,h,e,d]
    _Float16* x_hi = (_Float16*)(kvT + 131072);    // 32 MB
    _Float16* x_lo = x_hi + 16777216;              // 32 MB
    _Float16* w_hi = x_lo + 16777216;              // 1 MB
    _Float16* w_lo = w_hi + 524288;                // 1 MB

    hipMemsetAsync(pool_q, 0, (size_t)(3 * 4096 + 131072) * sizeof(float), stream);

    k_split<<<16384, 256, 0, stream>>>((const float4*)x, (half4*)x_hi, (half4*)x_lo, 4194304);
    k_split<<<512, 256, 0, stream>>>((const float4*)qk_w, (half4*)w_hi, (half4*)w_lo, 131072);
    k_gemm_mfma<<<dim3(256, 8), 256, 0, stream>>>(x_hi, x_lo, w_hi, w_lo, qk_b, qk);

    k_spatial<<<dim3(2048, 2), 512, 0, stream>>>(qk, x,
        qsp_dw_w, qsp_dw_b, qsp_bn_g, qsp_bn_b, qsp_pw_w,
        ksp_dw_w, ksp_dw_b, ksp_bn_g, ksp_bn_b, ksp_pw_w,
        lepe_w, lepe_b,
        s_sp_q, s_sp_k, pool_q, pool_k, (float*)d_out);
    k_chsig<<<2048, 256, 0, stream>>>(pool_q, pool_k, qch_w, kch_w, sch_q, sch_k);
    k_kv<<<dim3(128, 8), 256, 0, stream>>>(qk, x, s_sp_k, sch_k, rope_cos, rope_sin,
                                           kvT, kmean);
    k_attn<<<1024, 256, 0, stream>>>(qk, kvT, kmean, s_sp_q, sch_q,
                                     rope_cos, rope_sin, (float*)d_out);
}